// Round 8
// baseline (463.029 us; speedup 1.0000x reference)
//
#include <hip/hip_runtime.h>
#include <cstddef>

#define BSZ   8192
#define DIM   1024
#define NCON  64
#define NBANK 100000
#define NCLS  1000
#define TOPK  50
#define NCH2  64
#define CH2   1563     // 64 * 1563 = 100032 >= 100000

#define Y_OFF 8192000
#define S_OFF 16384000

typedef __attribute__((ext_vector_type(8))) short bf16x8;
typedef __attribute__((ext_vector_type(4))) float f32x4;

__device__ __forceinline__ short f2bf(float x) {
    unsigned u = __builtin_bit_cast(unsigned, x);
    unsigned r = (u + 0x7fffu + ((u >> 16) & 1u)) >> 16;
    return (short)r;
}

__device__ __forceinline__ bf16x8 pack8(f32x4 a, f32x4 b) {
    bf16x8 p;
    p[0] = f2bf(a[0]); p[1] = f2bf(a[1]); p[2] = f2bf(a[2]); p[3] = f2bf(a[3]);
    p[4] = f2bf(b[0]); p[5] = f2bf(b[1]); p[6] = f2bf(b[2]); p[7] = f2bf(b[3]);
    return p;
}

__device__ __forceinline__ void gload16(const short* g, short* l) {
    __builtin_amdgcn_global_load_lds(
        (__attribute__((address_space(1))) void*)g,
        (__attribute__((address_space(3))) void*)l,
        16, 0, 0);
}

// ================= L1: prep (all-parallel converts) =================
__global__ void __launch_bounds__(256) prep_kernel(const float* __restrict__ X,
                                                   const float* __restrict__ cpt,
                                                   const float* __restrict__ Wh,
                                                   short* __restrict__ Xbf,
                                                   short* __restrict__ WcatT,
                                                   short* __restrict__ cptT,
                                                   short* __restrict__ cptR) {
    __shared__ short Ts[64][65];
    int b = blockIdx.x;
    int t = threadIdx.x;
    if (b < 4096) {
        size_t u = ((size_t)b * 256 + t) * 8;
        f32x4 a = *(const f32x4*)(X + u);
        f32x4 c = *(const f32x4*)(X + u + 4);
        *(bf16x8*)(Xbf + u) = pack8(a, c);
    } else if (b < 4352) {
        int q = b - 4096;
        int k0 = (q & 15) * 64, n0 = (q >> 4) * 64;
        #pragma unroll
        for (int i = 0; i < 16; ++i) {
            int u = i * 256 + t;
            int kL = u >> 6, nL = u & 63;
            int n = n0 + nL;
            Ts[kL][nL] = (n < NCLS) ? f2bf(Wh[(size_t)(k0 + kL) * NCLS + n]) : (short)0;
        }
        __syncthreads();
        #pragma unroll
        for (int i = 0; i < 16; ++i) {
            int u = i * 256 + t;
            int nL = u >> 6, kL = u & 63;
            WcatT[(size_t)(n0 + nL) * DIM + k0 + kL] = Ts[kL][nL];
        }
    } else {
        int q = b - 4352;
        #pragma unroll
        for (int i = 0; i < 16; ++i) {
            int u = q * 4096 + i * 256 + t;
            int d = u >> 6, n = u & 63;
            short v = f2bf(cpt[u]);
            cptR[u] = v;
            cptT[n * DIM + d] = v;
        }
    }
}

// ================= L2: mid =================
// 0..781: dist (LDS-free MFMA) ; 782..789: M = C^T@Wh ; 790: G (MFMA) + invG (reg-GJ)
__global__ void __launch_bounds__(256) mid_kernel(const float* __restrict__ bank,
                                                  const short* __restrict__ cptT,
                                                  const short* __restrict__ WcatT,
                                                  float* __restrict__ key,
                                                  float* __restrict__ bank_sq,
                                                  float* __restrict__ M,
                                                  float* __restrict__ G,
                                                  float* __restrict__ invG) {
    __shared__ float rowk[64];
    __shared__ float fk[64];
    int b = blockIdx.x;
    int t = threadIdx.x;
    int wid = t >> 6, l = t & 63, lr = l & 15, lg = l >> 4;
    if (b < 782) {
        int j0 = b * 128;
        int j_[2]; bool v_[2];
        const float* brow[2];
        #pragma unroll
        for (int ni = 0; ni < 2; ++ni) {
            j_[ni] = j0 + wid * 32 + ni * 16 + lr;
            v_[ni] = j_[ni] < NBANK;
            brow[ni] = bank + (size_t)j_[ni] * DIM + lg * 8;
        }
        f32x4 acc[4][2] = {};
        float sq[2] = {0.f, 0.f};
        for (int kk = 0; kk < DIM; kk += 32) {
            bf16x8 af[4];
            #pragma unroll
            for (int mi = 0; mi < 4; ++mi)
                af[mi] = *(const bf16x8*)(cptT + (mi * 16 + lr) * DIM + kk + lg * 8);
            #pragma unroll
            for (int ni = 0; ni < 2; ++ni) {
                f32x4 a = v_[ni] ? *(const f32x4*)(brow[ni] + kk)     : f32x4{0.f, 0.f, 0.f, 0.f};
                f32x4 c = v_[ni] ? *(const f32x4*)(brow[ni] + kk + 4) : f32x4{0.f, 0.f, 0.f, 0.f};
                sq[ni] += a[0]*a[0] + a[1]*a[1] + a[2]*a[2] + a[3]*a[3]
                        + c[0]*c[0] + c[1]*c[1] + c[2]*c[2] + c[3]*c[3];
                bf16x8 bfr = pack8(a, c);
                #pragma unroll
                for (int mi = 0; mi < 4; ++mi)
                    acc[mi][ni] = __builtin_amdgcn_mfma_f32_16x16x32_bf16(af[mi], bfr, acc[mi][ni], 0, 0, 0);
            }
        }
        #pragma unroll
        for (int ni = 0; ni < 2; ++ni) {
            float s = sq[ni];
            s += __shfl_xor(s, 16);
            s += __shfl_xor(s, 32);
            sq[ni] = s;
            if (v_[ni] && lg == 0) bank_sq[j_[ni]] = s;
        }
        #pragma unroll
        for (int mi = 0; mi < 4; ++mi)
            #pragma unroll
            for (int ni = 0; ni < 2; ++ni)
                if (v_[ni]) {
                    #pragma unroll
                    for (int r = 0; r < 4; ++r) {
                        int m = mi * 16 + lg * 4 + r;
                        key[(size_t)m * NBANK + j_[ni]] = sq[ni] - 2.f * acc[mi][ni][r];
                    }
                }
    } else if (b < 790) {
        int c0 = (b - 782) * 128;
        f32x4 acc[4][2] = {};
        for (int kk = 0; kk < DIM; kk += 32) {
            bf16x8 af[4], bfr[2];
            #pragma unroll
            for (int mi = 0; mi < 4; ++mi)
                af[mi] = *(const bf16x8*)(cptT + (mi * 16 + lr) * DIM + kk + lg * 8);
            #pragma unroll
            for (int ni = 0; ni < 2; ++ni)
                bfr[ni] = *(const bf16x8*)(WcatT + (size_t)(c0 + wid * 32 + ni * 16 + lr) * DIM + kk + lg * 8);
            #pragma unroll
            for (int mi = 0; mi < 4; ++mi)
                #pragma unroll
                for (int ni = 0; ni < 2; ++ni)
                    acc[mi][ni] = __builtin_amdgcn_mfma_f32_16x16x32_bf16(af[mi], bfr[ni], acc[mi][ni], 0, 0, 0);
        }
        #pragma unroll
        for (int mi = 0; mi < 4; ++mi)
            #pragma unroll
            for (int ni = 0; ni < 2; ++ni)
                #pragma unroll
                for (int r = 0; r < 4; ++r)
                    M[(mi * 16 + lg * 4 + r) * 1024 + c0 + wid * 32 + ni * 16 + lr] = acc[mi][ni][r];
    } else {
        // --- G = C^T C via MFMA ---
        f32x4 acc[4] = {};
        for (int kk = 0; kk < DIM; kk += 32) {
            bf16x8 af[4], bfr;
            #pragma unroll
            for (int mi = 0; mi < 4; ++mi)
                af[mi] = *(const bf16x8*)(cptT + (mi * 16 + lr) * DIM + kk + lg * 8);
            bfr = *(const bf16x8*)(cptT + (wid * 16 + lr) * DIM + kk + lg * 8);
            #pragma unroll
            for (int mi = 0; mi < 4; ++mi)
                acc[mi] = __builtin_amdgcn_mfma_f32_16x16x32_bf16(af[mi], bfr, acc[mi], 0, 0, 0);
        }
        #pragma unroll
        for (int mi = 0; mi < 4; ++mi)
            #pragma unroll
            for (int r = 0; r < 4; ++r)
                G[(mi * 16 + lg * 4 + r) * 64 + wid * 16 + lr] = acc[mi][r];
        __syncthreads();   // drain vmcnt: G visible to own reads via L2
        // --- in-place Gauss-Jordan inverse, matrix in registers ---
        float myA[16];
        #pragma unroll
        for (int s = 0; s < 16; ++s) myA[s] = G[(4 * s + wid) * 64 + l];
        #pragma unroll
        for (int k = 0; k < 64; ++k) {
            if (wid == (k & 3)) rowk[l] = myA[k >> 2];
            if (l == k) {
                #pragma unroll
                for (int s = 0; s < 16; ++s) fk[4 * s + wid] = myA[s];
            }
            __syncthreads();
            float ip = 1.f / rowk[k];
            float rv = rowk[l];
            #pragma unroll
            for (int s = 0; s < 16; ++s) {
                int i = 4 * s + wid;
                float fv = fk[i];
                float nv;
                if (i == k && l == k)      nv = ip;
                else if (i == k)           nv = rv * ip;
                else if (l == k)           nv = -fv * ip;
                else                       nv = myA[s] - fv * (rv * ip);
                myA[s] = nv;
            }
            __syncthreads();
        }
        #pragma unroll
        for (int s = 0; s < 16; ++s) invG[(4 * s + wid) * 64 + l] = myA[s];
    }
}

// ================= L3: topA v3 — single-wave, all-register, barrier-free =================
// block = concept*64 + chunk(1563). Thread t owns r[i] = key[base + t + i*64], i<25.
// Each slot only ever touched by its owner -> no LDS, no barriers; cross-thread
// communication is shuffle-only. Kill+rescan uses static indices (unrolled cmp).
__global__ void __launch_bounds__(64) topA_kernel(const float* __restrict__ key,
                                                  float* __restrict__ cand_v,
                                                  int* __restrict__ cand_j) {
    int n = blockIdx.x >> 6;
    int c = blockIdx.x & 63;
    int base = c * CH2;
    const float* row = key + (size_t)n * NBANK + base;
    int t = threadIdx.x;
    float r[25];
    float lv = __builtin_inff();
    int lj = 0x7fffffff;
    #pragma unroll
    for (int i = 0; i < 25; ++i) {
        int j = t + i * 64;
        bool ok = (j < CH2) && (base + j < NBANK);
        float v = ok ? row[j] : __builtin_inff();
        r[i] = v;
        if (v < lv) { lv = v; lj = j; }   // ascending j -> strict < keeps earliest
    }
    float* cv = cand_v + (size_t)blockIdx.x * TOPK;
    int* cj = cand_j + (size_t)blockIdx.x * TOPK;
    for (int it = 0; it < TOPK; ++it) {
        float bv = lv; int bj = lj;
        #pragma unroll
        for (int o = 32; o > 0; o >>= 1) {
            float ov = __shfl_down(bv, o);
            int oj = __shfl_down(bj, o);
            if (ov < bv || (ov == bv && oj < bj)) { bv = ov; bj = oj; }
        }
        bv = __shfl(bv, 0);
        bj = __shfl(bj, 0);
        if (t == 0) { cv[it] = bv; cj[it] = base + bj; }
        if ((bj & 63) == t) {     // owner thread: kill winner, rescan own 25
            lv = __builtin_inff(); lj = 0x7fffffff;
            #pragma unroll
            for (int i = 0; i < 25; ++i) {
                if (t + i * 64 == bj) r[i] = __builtin_inff();
                float v = r[i];
                if (v < lv) { lv = v; lj = t + i * 64; }
            }
        }
    }
}

// ================= L4: m2w2 + topB (merge 64*50 candidates) =================
__global__ void __launch_bounds__(256) m2w2_topB_kernel(const float* __restrict__ invG,
                                                        const float* __restrict__ M,
                                                        const short* __restrict__ cptR,
                                                        short* __restrict__ WcatT,
                                                        const float* __restrict__ cand_v,
                                                        const int* __restrict__ cand_j,
                                                        const float* __restrict__ bank_sq,
                                                        float* __restrict__ dots) {
    __shared__ __align__(16) char smem[49408];
    int b = blockIdx.x;
    int t = threadIdx.x;
    if (b < 8) {
        float* Mt = (float*)smem;            // [64][129]
        short* M2s = (short*)(smem + 33024); // [128][64] XOR-swizzled rows
        int c0 = b * 128;
        for (int u = t; u < 8192; u += 256) {
            int j = u >> 7, cc = u & 127;
            Mt[j * 129 + cc] = M[j * 1024 + c0 + cc];
        }
        __syncthreads();
        int cl = t & 127, half = t >> 7;
        for (int nn = 0; nn < 32; ++nn) {
            int n = half * 32 + nn;
            float a = 0.f;
            #pragma unroll 16
            for (int j = 0; j < 64; ++j) a += invG[n * 64 + j] * Mt[j * 129 + cl];
            int s = n >> 3;
            M2s[cl * 64 + (((s ^ (cl & 7)) << 3) | (n & 7))] = f2bf(a);
        }
        __syncthreads();
        int wid = t >> 6, l = t & 63, lr = l & 15, lg = l >> 4;
        int wr = wid >> 1, wc = wid & 1;
        for (int d0 = 0; d0 < DIM; d0 += 128) {
            f32x4 acc[4][4] = {};
            #pragma unroll
            for (int ks = 0; ks < 2; ++ks) {
                bf16x8 af[4], bfr[4];
                #pragma unroll
                for (int mi = 0; mi < 4; ++mi) {
                    int rr = wr * 64 + mi * 16 + lr;
                    int slot = (ks * 4 + lg) ^ (rr & 7);
                    af[mi] = *(const bf16x8*)(M2s + rr * 64 + slot * 8);
                }
                #pragma unroll
                for (int ni = 0; ni < 4; ++ni)
                    bfr[ni] = *(const bf16x8*)(cptR + (size_t)(d0 + wc * 64 + ni * 16 + lr) * 64 + ks * 32 + lg * 8);
                #pragma unroll
                for (int mi = 0; mi < 4; ++mi)
                    #pragma unroll
                    for (int ni = 0; ni < 4; ++ni)
                        acc[mi][ni] = __builtin_amdgcn_mfma_f32_16x16x32_bf16(af[mi], bfr[ni], acc[mi][ni], 0, 0, 0);
            }
            #pragma unroll
            for (int mi = 0; mi < 4; ++mi)
                #pragma unroll
                for (int ni = 0; ni < 4; ++ni)
                    #pragma unroll
                    for (int r = 0; r < 4; ++r) {
                        int cc = c0 + wr * 64 + mi * 16 + lg * 4 + r;
                        int d = d0 + wc * 64 + ni * 16 + lr;
                        WcatT[(size_t)(1024 + cc) * DIM + d] = f2bf(acc[mi][ni][r]);
                    }
        }
    } else {
        int n = b - 8;
        const int NC2 = NCH2 * TOPK;  // 3200
        float* vals = (float*)smem;                 // 12800 B
        int* gidx = (int*)(smem + 12800);           // 12800 B
        float* wv = (float*)(smem + 25600);
        int* wj = (int*)(smem + 25616);
        int* wl = (int*)(smem + 25632);
        for (int j = t; j < NC2; j += 256) {
            vals[j] = cand_v[(size_t)n * NC2 + j];
            gidx[j] = cand_j[(size_t)n * NC2 + j];
        }
        __syncthreads();
        float sum = 0.f;
        for (int it = 0; it < TOPK; ++it) {
            float bv = __builtin_inff();
            int bj = 0x7fffffff;
            int bl = -1;
            for (int j = t; j < NC2; j += 256) {
                float v = vals[j];
                int gj = gidx[j];
                if (v < bv || (v == bv && gj < bj)) { bv = v; bj = gj; bl = j; }
            }
            #pragma unroll
            for (int o = 32; o > 0; o >>= 1) {
                float ov = __shfl_down(bv, o);
                int oj = __shfl_down(bj, o);
                int ol = __shfl_down(bl, o);
                if (ov < bv || (ov == bv && oj < bj)) { bv = ov; bj = oj; bl = ol; }
            }
            if ((t & 63) == 0) { wv[t >> 6] = bv; wj[t >> 6] = bj; wl[t >> 6] = bl; }
            __syncthreads();
            if (t == 0) {
                #pragma unroll
                for (int w = 1; w < 4; ++w)
                    if (wv[w] < bv || (wv[w] == bv && wj[w] < bj)) { bv = wv[w]; bj = wj[w]; bl = wl[w]; }
                sum += 0.5f * (bank_sq[bj] - bv);
                vals[bl] = __builtin_inff();
            }
            __syncthreads();
        }
        if (t == 0) dots[n] = sum / (float)TOPK;
    }
}

// ================= L5: pred + finalize =================
__global__ void __launch_bounds__(256) pred_fin_kernel(const short* __restrict__ Xbf,
                                                       const short* __restrict__ WcatT,
                                                       const float* __restrict__ bh,
                                                       const float* __restrict__ G,
                                                       const float* __restrict__ dots,
                                                       float* __restrict__ orig,
                                                       float* __restrict__ ypred,
                                                       float* __restrict__ out3) {
    __shared__ __align__(16) char smem[32768];
    int b = blockIdx.x;
    int t = threadIdx.x;
    if (b < 1024) {
        short* As = (short*)smem;            // [128][64] bf16
        short* Bs = (short*)(smem + 16384);
        int c0 = (b & 15) * 128;
        int r0 = (b >> 4) * 128;
        int wid = t >> 6, l = t & 63, lr = l & 15, lg = l >> 4;
        int wr = wid >> 1, wc = wid & 1;
        int srow_off = l >> 3;
        int scol = ((l & 7) ^ (l >> 3)) * 8;
        f32x4 acc[4][4] = {};
        for (int kk = 0; kk < DIM; kk += 64) {
            if (kk) __syncthreads();
            #pragma unroll
            for (int i = 0; i < 4; ++i) {
                int si = wid * 4 + i;
                int row = si * 8 + srow_off;
                gload16(Xbf + (size_t)(r0 + row) * DIM + kk + scol, As + si * 512);
                gload16(WcatT + (size_t)(c0 + row) * DIM + kk + scol, Bs + si * 512);
            }
            __syncthreads();
            #pragma unroll
            for (int ks = 0; ks < 2; ++ks) {
                bf16x8 af[4], bfr[4];
                #pragma unroll
                for (int mi = 0; mi < 4; ++mi) {
                    int rr = wr * 64 + mi * 16 + lr;
                    int slot = (ks * 4 + lg) ^ (rr & 7);
                    af[mi] = *(const bf16x8*)(As + rr * 64 + slot * 8);
                }
                #pragma unroll
                for (int ni = 0; ni < 4; ++ni) {
                    int cc = wc * 64 + ni * 16 + lr;
                    int slot = (ks * 4 + lg) ^ (cc & 7);
                    bfr[ni] = *(const bf16x8*)(Bs + cc * 64 + slot * 8);
                }
                #pragma unroll
                for (int mi = 0; mi < 4; ++mi)
                    #pragma unroll
                    for (int ni = 0; ni < 4; ++ni)
                        acc[mi][ni] = __builtin_amdgcn_mfma_f32_16x16x32_bf16(af[mi], bfr[ni], acc[mi][ni], 0, 0, 0);
            }
        }
        #pragma unroll
        for (int mi = 0; mi < 4; ++mi)
            #pragma unroll
            for (int ni = 0; ni < 4; ++ni) {
                int cg = c0 + wc * 64 + ni * 16 + lr;
                bool isorig = cg < NCLS;
                bool isy = (cg >= 1024) && (cg < 1024 + NCLS);
                if (isorig || isy) {
                    int cl = isorig ? cg : cg - 1024;
                    float bias = bh[cl];
                    float* dst = isorig ? orig : ypred;
                    #pragma unroll
                    for (int r = 0; r < 4; ++r) {
                        int row = r0 + wr * 64 + mi * 16 + lg * 4 + r;
                        dst[(size_t)row * NCLS + cl] = acc[mi][ni][r] + bias;
                    }
                }
            }
    } else {
        float* r1 = (float*)smem;
        float* r2 = (float*)(smem + 1024);
        float* r3 = (float*)(smem + 2048);
        float sd = 0.f, so = 0.f;
        for (int u = t; u < 4096; u += 256) {
            float g = G[u];
            if ((u >> 6) == (u & 63)) sd += g; else so += g;
        }
        float s1 = (t < NCON) ? dots[t] : 0.f;
        r1[t] = sd; r2[t] = so; r3[t] = s1;
        __syncthreads();
        for (int o = 128; o > 0; o >>= 1) {
            if (t < o) { r1[t] += r1[t + o]; r2[t] += r2[t + o]; r3[t] += r3[t + o]; }
            __syncthreads();
        }
        if (t == 0) {
            out3[0] = r3[0] / 64.f;
            out3[1] = r2[0] / 4096.f;
            out3[2] = r1[0] / 4096.f;
        }
    }
}

extern "C" void kernel_launch(void* const* d_in, const int* in_sizes, int n_in,
                              void* d_out, int out_size, void* d_ws, size_t ws_size,
                              hipStream_t stream) {
    const float* X    = (const float*)d_in[0];
    const float* cpt  = (const float*)d_in[1];
    const float* bank = (const float*)d_in[2];
    const float* Wh   = (const float*)d_in[3];
    const float* bh   = (const float*)d_in[4];
    float* out = (float*)d_out;

    float* orig  = out;
    float* ypred = out + Y_OFF;
    float* out3  = out + S_OFF;

    char* w = (char*)d_ws;
    short* Xbf    = (short*)(w);               // 16,777,216 B
    short* WcatT  = (short*)(w + 16777216);    //  4,194,304 B
    short* cptT   = (short*)(w + 20971520);    //    131,072 B
    short* cptR   = (short*)(w + 21102592);    //    131,072 B
    float* key    = (float*)(w + 21233664);    // 25,600,000 B
    float* bank_sq= (float*)(w + 46833664);    //    400,384 B
    float* G      = (float*)(w + 47234048);    //     16,384 B
    float* invG   = (float*)(w + 47250432);    //     16,384 B
    float* M      = (float*)(w + 47266816);    //    262,144 B
    float* cand_v = (float*)(w + 47528960);    //    819,200 B (64*64*50 f32)
    int*   cand_j = (int*)  (w + 48348160);    //    819,200 B
    float* dots   = (float*)(w + 49167360);    //        256 B

    prep_kernel<<<4368, 256, 0, stream>>>(X, cpt, Wh, Xbf, WcatT, cptT, cptR);
    mid_kernel<<<791, 256, 0, stream>>>(bank, cptT, WcatT, key, bank_sq, M, G, invG);
    topA_kernel<<<NCON * NCH2, 64, 0, stream>>>(key, cand_v, cand_j);
    m2w2_topB_kernel<<<72, 256, 0, stream>>>(invG, M, cptR, WcatT, cand_v, cand_j, bank_sq, dots);
    pred_fin_kernel<<<1025, 256, 0, stream>>>(Xbf, WcatT, bh, G, dots, orig, ypred, out3);
}

// Round 9
// 424.834 us; speedup vs baseline: 1.0899x; 1.0899x over previous
//
#include <hip/hip_runtime.h>
#include <cstddef>

#define BSZ   8192
#define DIM   1024
#define NCON  64
#define NBANK 100000
#define NCLS  1000
#define TOPK  50
#define NCHUNK 32
#define CHUNK  3125    // 32 * 3125 = 100000
#define CHUNKP 3328    // 13 * 256 (padded with +inf)

#define Y_OFF 8192000
#define S_OFF 16384000

typedef __attribute__((ext_vector_type(8))) short bf16x8;
typedef __attribute__((ext_vector_type(4))) float f32x4;

__device__ __forceinline__ short f2bf(float x) {
    unsigned u = __builtin_bit_cast(unsigned, x);
    unsigned r = (u + 0x7fffu + ((u >> 16) & 1u)) >> 16;
    return (short)r;
}

__device__ __forceinline__ bf16x8 pack8(f32x4 a, f32x4 b) {
    bf16x8 p;
    p[0] = f2bf(a[0]); p[1] = f2bf(a[1]); p[2] = f2bf(a[2]); p[3] = f2bf(a[3]);
    p[4] = f2bf(b[0]); p[5] = f2bf(b[1]); p[6] = f2bf(b[2]); p[7] = f2bf(b[3]);
    return p;
}

__device__ __forceinline__ void gload16(const short* g, short* l) {
    __builtin_amdgcn_global_load_lds(
        (__attribute__((address_space(1))) void*)g,
        (__attribute__((address_space(3))) void*)l,
        16, 0, 0);
}

// ================= L1: prep (only what mid depends on) =================
// 0..255: Wh^T->bf16 (padded) ; 256..271: cpt->cptT,cptR
__global__ void __launch_bounds__(256) prep_kernel(const float* __restrict__ cpt,
                                                   const float* __restrict__ Wh,
                                                   short* __restrict__ WcatT,
                                                   short* __restrict__ cptT,
                                                   short* __restrict__ cptR) {
    __shared__ short Ts[64][65];
    int b = blockIdx.x;
    int t = threadIdx.x;
    if (b < 256) {
        int k0 = (b & 15) * 64, n0 = (b >> 4) * 64;
        #pragma unroll
        for (int i = 0; i < 16; ++i) {
            int u = i * 256 + t;
            int kL = u >> 6, nL = u & 63;
            int n = n0 + nL;
            Ts[kL][nL] = (n < NCLS) ? f2bf(Wh[(size_t)(k0 + kL) * NCLS + n]) : (short)0;
        }
        __syncthreads();
        #pragma unroll
        for (int i = 0; i < 16; ++i) {
            int u = i * 256 + t;
            int nL = u >> 6, kL = u & 63;
            WcatT[(size_t)(n0 + nL) * DIM + k0 + kL] = Ts[kL][nL];
        }
    } else {
        int q = b - 256;
        #pragma unroll
        for (int i = 0; i < 16; ++i) {
            int u = q * 4096 + i * 256 + t;
            int d = u >> 6, n = u & 63;
            short v = f2bf(cpt[u]);
            cptR[u] = v;
            cptT[n * DIM + d] = v;
        }
    }
}

// ================= L2: mid =================
// 0..781: dist ; 782..789: M = C^T@Wh ; 790: G + invG (reg-GJ) ; 791..4886: X->bf16
__global__ void __launch_bounds__(256) mid_kernel(const float* __restrict__ bank,
                                                  const float* __restrict__ X,
                                                  const short* __restrict__ cptT,
                                                  const short* __restrict__ WcatT,
                                                  short* __restrict__ Xbf,
                                                  float* __restrict__ key,
                                                  float* __restrict__ bank_sq,
                                                  float* __restrict__ M,
                                                  float* __restrict__ G,
                                                  float* __restrict__ invG) {
    __shared__ float rowk[64];
    __shared__ float fk[64];
    int b = blockIdx.x;
    int t = threadIdx.x;
    int wid = t >> 6, l = t & 63, lr = l & 15, lg = l >> 4;
    if (b < 782) {
        int j0 = b * 128;
        int j_[2]; bool v_[2];
        const float* brow[2];
        #pragma unroll
        for (int ni = 0; ni < 2; ++ni) {
            j_[ni] = j0 + wid * 32 + ni * 16 + lr;
            v_[ni] = j_[ni] < NBANK;
            brow[ni] = bank + (size_t)j_[ni] * DIM + lg * 8;
        }
        f32x4 acc[4][2] = {};
        float sq[2] = {0.f, 0.f};
        for (int kk = 0; kk < DIM; kk += 32) {
            bf16x8 af[4];
            #pragma unroll
            for (int mi = 0; mi < 4; ++mi)
                af[mi] = *(const bf16x8*)(cptT + (mi * 16 + lr) * DIM + kk + lg * 8);
            #pragma unroll
            for (int ni = 0; ni < 2; ++ni) {
                f32x4 a = v_[ni] ? *(const f32x4*)(brow[ni] + kk)     : f32x4{0.f, 0.f, 0.f, 0.f};
                f32x4 c = v_[ni] ? *(const f32x4*)(brow[ni] + kk + 4) : f32x4{0.f, 0.f, 0.f, 0.f};
                sq[ni] += a[0]*a[0] + a[1]*a[1] + a[2]*a[2] + a[3]*a[3]
                        + c[0]*c[0] + c[1]*c[1] + c[2]*c[2] + c[3]*c[3];
                bf16x8 bfr = pack8(a, c);
                #pragma unroll
                for (int mi = 0; mi < 4; ++mi)
                    acc[mi][ni] = __builtin_amdgcn_mfma_f32_16x16x32_bf16(af[mi], bfr, acc[mi][ni], 0, 0, 0);
            }
        }
        #pragma unroll
        for (int ni = 0; ni < 2; ++ni) {
            float s = sq[ni];
            s += __shfl_xor(s, 16);
            s += __shfl_xor(s, 32);
            sq[ni] = s;
            if (v_[ni] && lg == 0) bank_sq[j_[ni]] = s;
        }
        #pragma unroll
        for (int mi = 0; mi < 4; ++mi)
            #pragma unroll
            for (int ni = 0; ni < 2; ++ni)
                if (v_[ni]) {
                    #pragma unroll
                    for (int r = 0; r < 4; ++r) {
                        int m = mi * 16 + lg * 4 + r;
                        key[(size_t)m * NBANK + j_[ni]] = sq[ni] - 2.f * acc[mi][ni][r];
                    }
                }
    } else if (b < 790) {
        int c0 = (b - 782) * 128;
        f32x4 acc[4][2] = {};
        for (int kk = 0; kk < DIM; kk += 32) {
            bf16x8 af[4], bfr[2];
            #pragma unroll
            for (int mi = 0; mi < 4; ++mi)
                af[mi] = *(const bf16x8*)(cptT + (mi * 16 + lr) * DIM + kk + lg * 8);
            #pragma unroll
            for (int ni = 0; ni < 2; ++ni)
                bfr[ni] = *(const bf16x8*)(WcatT + (size_t)(c0 + wid * 32 + ni * 16 + lr) * DIM + kk + lg * 8);
            #pragma unroll
            for (int mi = 0; mi < 4; ++mi)
                #pragma unroll
                for (int ni = 0; ni < 2; ++ni)
                    acc[mi][ni] = __builtin_amdgcn_mfma_f32_16x16x32_bf16(af[mi], bfr[ni], acc[mi][ni], 0, 0, 0);
        }
        #pragma unroll
        for (int mi = 0; mi < 4; ++mi)
            #pragma unroll
            for (int ni = 0; ni < 2; ++ni)
                #pragma unroll
                for (int r = 0; r < 4; ++r)
                    M[(mi * 16 + lg * 4 + r) * 1024 + c0 + wid * 32 + ni * 16 + lr] = acc[mi][ni][r];
    } else if (b == 790) {
        // --- G = C^T C via MFMA ---
        f32x4 acc[4] = {};
        for (int kk = 0; kk < DIM; kk += 32) {
            bf16x8 af[4], bfr;
            #pragma unroll
            for (int mi = 0; mi < 4; ++mi)
                af[mi] = *(const bf16x8*)(cptT + (mi * 16 + lr) * DIM + kk + lg * 8);
            bfr = *(const bf16x8*)(cptT + (wid * 16 + lr) * DIM + kk + lg * 8);
            #pragma unroll
            for (int mi = 0; mi < 4; ++mi)
                acc[mi] = __builtin_amdgcn_mfma_f32_16x16x32_bf16(af[mi], bfr, acc[mi], 0, 0, 0);
        }
        #pragma unroll
        for (int mi = 0; mi < 4; ++mi)
            #pragma unroll
            for (int r = 0; r < 4; ++r)
                G[(mi * 16 + lg * 4 + r) * 64 + wid * 16 + lr] = acc[mi][r];
        __syncthreads();   // drain vmcnt: G visible to own reads via L2
        // --- in-place Gauss-Jordan inverse, matrix in registers ---
        float myA[16];
        #pragma unroll
        for (int s = 0; s < 16; ++s) myA[s] = G[(4 * s + wid) * 64 + l];
        #pragma unroll
        for (int k = 0; k < 64; ++k) {
            if (wid == (k & 3)) rowk[l] = myA[k >> 2];
            if (l == k) {
                #pragma unroll
                for (int s = 0; s < 16; ++s) fk[4 * s + wid] = myA[s];
            }
            __syncthreads();
            float ip = 1.f / rowk[k];
            float rv = rowk[l];
            #pragma unroll
            for (int s = 0; s < 16; ++s) {
                int i = 4 * s + wid;
                float fv = fk[i];
                float nv;
                if (i == k && l == k)      nv = ip;
                else if (i == k)           nv = rv * ip;
                else if (l == k)           nv = -fv * ip;
                else                       nv = myA[s] - fv * (rv * ip);
                myA[s] = nv;
            }
            __syncthreads();
        }
        #pragma unroll
        for (int s = 0; s < 16; ++s) invG[(4 * s + wid) * 64 + l] = myA[s];
    } else {
        size_t u = ((size_t)(b - 791) * 256 + t) * 8;
        f32x4 a = *(const f32x4*)(X + u);
        f32x4 c = *(const f32x4*)(X + u + 4);
        *(bf16x8*)(Xbf + u) = pack8(a, c);
    }
}

// ================= L3: topA (v2: cached min + owner rescan) =================
__global__ void __launch_bounds__(256) topA_kernel(const float* __restrict__ key,
                                                   float* __restrict__ cand_v,
                                                   int* __restrict__ cand_j) {
    int n = blockIdx.x >> 5;
    int c = blockIdx.x & 31;
    int base = c * CHUNK;
    const float* row = key + (size_t)n * NBANK + base;
    __shared__ float vals[CHUNKP];
    __shared__ float wv[4];
    __shared__ int wj[4];
    int t = threadIdx.x;
    float lv = __builtin_inff();
    int lj = 0x7fffffff;
    #pragma unroll 13
    for (int i = 0; i < 13; ++i) {
        int j = t + i * 256;
        float v = (j < CHUNK) ? row[j] : __builtin_inff();
        vals[j] = v;
        if (v < lv) { lv = v; lj = j; }
    }
    __syncthreads();
    float* cv = cand_v + (size_t)blockIdx.x * TOPK;
    int* cj = cand_j + (size_t)blockIdx.x * TOPK;
    for (int it = 0; it < TOPK; ++it) {
        float bv = lv; int bj = lj;
        #pragma unroll
        for (int o = 32; o > 0; o >>= 1) {
            float ov = __shfl_down(bv, o);
            int oj = __shfl_down(bj, o);
            if (ov < bv || (ov == bv && oj < bj)) { bv = ov; bj = oj; }
        }
        if ((t & 63) == 0) { wv[t >> 6] = bv; wj[t >> 6] = bj; }
        __syncthreads();
        float gv = wv[0]; int gj = wj[0];
        #pragma unroll
        for (int w = 1; w < 4; ++w)
            if (wv[w] < gv || (wv[w] == gv && wj[w] < gj)) { gv = wv[w]; gj = wj[w]; }
        if (t == 0) { cv[it] = gv; cj[it] = base + gj; }
        if (t == (gj & 255)) {
            vals[gj] = __builtin_inff();
            lv = __builtin_inff(); lj = 0x7fffffff;
            #pragma unroll 13
            for (int i = 0; i < 13; ++i) {
                int j = t + i * 256;
                float v = vals[j];
                if (v < lv) { lv = v; lj = j; }
            }
        }
        __syncthreads();
    }
}

// ================= L4: m2w2 + topB =================
__global__ void __launch_bounds__(256) m2w2_topB_kernel(const float* __restrict__ invG,
                                                        const float* __restrict__ M,
                                                        const short* __restrict__ cptR,
                                                        short* __restrict__ WcatT,
                                                        const float* __restrict__ cand_v,
                                                        const int* __restrict__ cand_j,
                                                        const float* __restrict__ bank_sq,
                                                        float* __restrict__ dots) {
    __shared__ __align__(16) char smem[49408];
    int b = blockIdx.x;
    int t = threadIdx.x;
    if (b < 8) {
        float* Mt = (float*)smem;            // [64][129]
        short* M2s = (short*)(smem + 33024); // [128][64] XOR-swizzled rows
        int c0 = b * 128;
        for (int u = t; u < 8192; u += 256) {
            int j = u >> 7, cc = u & 127;
            Mt[j * 129 + cc] = M[j * 1024 + c0 + cc];
        }
        __syncthreads();
        int cl = t & 127, half = t >> 7;
        for (int nn = 0; nn < 32; ++nn) {
            int n = half * 32 + nn;
            float a = 0.f;
            #pragma unroll 16
            for (int j = 0; j < 64; ++j) a += invG[n * 64 + j] * Mt[j * 129 + cl];
            int s = n >> 3;
            M2s[cl * 64 + (((s ^ (cl & 7)) << 3) | (n & 7))] = f2bf(a);
        }
        __syncthreads();
        int wid = t >> 6, l = t & 63, lr = l & 15, lg = l >> 4;
        int wr = wid >> 1, wc = wid & 1;
        for (int d0 = 0; d0 < DIM; d0 += 128) {
            f32x4 acc[4][4] = {};
            #pragma unroll
            for (int ks = 0; ks < 2; ++ks) {
                bf16x8 af[4], bfr[4];
                #pragma unroll
                for (int mi = 0; mi < 4; ++mi) {
                    int rr = wr * 64 + mi * 16 + lr;
                    int slot = (ks * 4 + lg) ^ (rr & 7);
                    af[mi] = *(const bf16x8*)(M2s + rr * 64 + slot * 8);
                }
                #pragma unroll
                for (int ni = 0; ni < 4; ++ni)
                    bfr[ni] = *(const bf16x8*)(cptR + (size_t)(d0 + wc * 64 + ni * 16 + lr) * 64 + ks * 32 + lg * 8);
                #pragma unroll
                for (int mi = 0; mi < 4; ++mi)
                    #pragma unroll
                    for (int ni = 0; ni < 4; ++ni)
                        acc[mi][ni] = __builtin_amdgcn_mfma_f32_16x16x32_bf16(af[mi], bfr[ni], acc[mi][ni], 0, 0, 0);
            }
            #pragma unroll
            for (int mi = 0; mi < 4; ++mi)
                #pragma unroll
                for (int ni = 0; ni < 4; ++ni)
                    #pragma unroll
                    for (int r = 0; r < 4; ++r) {
                        int cc = c0 + wr * 64 + mi * 16 + lg * 4 + r;
                        int d = d0 + wc * 64 + ni * 16 + lr;
                        WcatT[(size_t)(1024 + cc) * DIM + d] = f2bf(acc[mi][ni][r]);
                    }
        }
    } else {
        int n = b - 8;
        const int NC2 = NCHUNK * TOPK;  // 1600
        float* vals = (float*)smem;
        int* gidx = (int*)(smem + 6400);
        float* wv = (float*)(smem + 12800);
        int* wj = (int*)(smem + 12816);
        int* wl = (int*)(smem + 12832);
        for (int j = t; j < NC2; j += 256) {
            vals[j] = cand_v[(size_t)n * NC2 + j];
            gidx[j] = cand_j[(size_t)n * NC2 + j];
        }
        __syncthreads();
        float sum = 0.f;
        for (int it = 0; it < TOPK; ++it) {
            float bv = __builtin_inff();
            int bj = 0x7fffffff;
            int bl = -1;
            #pragma unroll 7
            for (int j = t; j < NC2; j += 256) {
                float v = vals[j];
                int gj = gidx[j];
                if (v < bv || (v == bv && gj < bj)) { bv = v; bj = gj; bl = j; }
            }
            #pragma unroll
            for (int o = 32; o > 0; o >>= 1) {
                float ov = __shfl_down(bv, o);
                int oj = __shfl_down(bj, o);
                int ol = __shfl_down(bl, o);
                if (ov < bv || (ov == bv && oj < bj)) { bv = ov; bj = oj; bl = ol; }
            }
            if ((t & 63) == 0) { wv[t >> 6] = bv; wj[t >> 6] = bj; wl[t >> 6] = bl; }
            __syncthreads();
            if (t == 0) {
                #pragma unroll
                for (int w = 1; w < 4; ++w)
                    if (wv[w] < bv || (wv[w] == bv && wj[w] < bj)) { bv = wv[w]; bj = wj[w]; bl = wl[w]; }
                sum += 0.5f * (bank_sq[bj] - bv);
                vals[bl] = __builtin_inff();
            }
            __syncthreads();
        }
        if (t == 0) dots[n] = sum / (float)TOPK;
    }
}

// ================= L5: pred + finalize =================
__global__ void __launch_bounds__(256) pred_fin_kernel(const short* __restrict__ Xbf,
                                                       const short* __restrict__ WcatT,
                                                       const float* __restrict__ bh,
                                                       const float* __restrict__ G,
                                                       const float* __restrict__ dots,
                                                       float* __restrict__ orig,
                                                       float* __restrict__ ypred,
                                                       float* __restrict__ out3) {
    __shared__ __align__(16) char smem[32768];
    int b = blockIdx.x;
    int t = threadIdx.x;
    if (b < 1024) {
        short* As = (short*)smem;            // [128][64] bf16
        short* Bs = (short*)(smem + 16384);
        int c0 = (b & 15) * 128;
        int r0 = (b >> 4) * 128;
        int wid = t >> 6, l = t & 63, lr = l & 15, lg = l >> 4;
        int wr = wid >> 1, wc = wid & 1;
        int srow_off = l >> 3;
        int scol = ((l & 7) ^ (l >> 3)) * 8;
        f32x4 acc[4][4] = {};
        for (int kk = 0; kk < DIM; kk += 64) {
            if (kk) __syncthreads();
            #pragma unroll
            for (int i = 0; i < 4; ++i) {
                int si = wid * 4 + i;
                int row = si * 8 + srow_off;
                gload16(Xbf + (size_t)(r0 + row) * DIM + kk + scol, As + si * 512);
                gload16(WcatT + (size_t)(c0 + row) * DIM + kk + scol, Bs + si * 512);
            }
            __syncthreads();
            #pragma unroll
            for (int ks = 0; ks < 2; ++ks) {
                bf16x8 af[4], bfr[4];
                #pragma unroll
                for (int mi = 0; mi < 4; ++mi) {
                    int rr = wr * 64 + mi * 16 + lr;
                    int slot = (ks * 4 + lg) ^ (rr & 7);
                    af[mi] = *(const bf16x8*)(As + rr * 64 + slot * 8);
                }
                #pragma unroll
                for (int ni = 0; ni < 4; ++ni) {
                    int cc = wc * 64 + ni * 16 + lr;
                    int slot = (ks * 4 + lg) ^ (cc & 7);
                    bfr[ni] = *(const bf16x8*)(Bs + cc * 64 + slot * 8);
                }
                #pragma unroll
                for (int mi = 0; mi < 4; ++mi)
                    #pragma unroll
                    for (int ni = 0; ni < 4; ++ni)
                        acc[mi][ni] = __builtin_amdgcn_mfma_f32_16x16x32_bf16(af[mi], bfr[ni], acc[mi][ni], 0, 0, 0);
            }
        }
        #pragma unroll
        for (int mi = 0; mi < 4; ++mi)
            #pragma unroll
            for (int ni = 0; ni < 4; ++ni) {
                int cg = c0 + wc * 64 + ni * 16 + lr;
                bool isorig = cg < NCLS;
                bool isy = (cg >= 1024) && (cg < 1024 + NCLS);
                if (isorig || isy) {
                    int cl = isorig ? cg : cg - 1024;
                    float bias = bh[cl];
                    float* dst = isorig ? orig : ypred;
                    #pragma unroll
                    for (int r = 0; r < 4; ++r) {
                        int row = r0 + wr * 64 + mi * 16 + lg * 4 + r;
                        dst[(size_t)row * NCLS + cl] = acc[mi][ni][r] + bias;
                    }
                }
            }
    } else {
        float* r1 = (float*)smem;
        float* r2 = (float*)(smem + 1024);
        float* r3 = (float*)(smem + 2048);
        float sd = 0.f, so = 0.f;
        for (int u = t; u < 4096; u += 256) {
            float g = G[u];
            if ((u >> 6) == (u & 63)) sd += g; else so += g;
        }
        float s1 = (t < NCON) ? dots[t] : 0.f;
        r1[t] = sd; r2[t] = so; r3[t] = s1;
        __syncthreads();
        for (int o = 128; o > 0; o >>= 1) {
            if (t < o) { r1[t] += r1[t + o]; r2[t] += r2[t + o]; r3[t] += r3[t + o]; }
            __syncthreads();
        }
        if (t == 0) {
            out3[0] = r3[0] / 64.f;
            out3[1] = r2[0] / 4096.f;
            out3[2] = r1[0] / 4096.f;
        }
    }
}

extern "C" void kernel_launch(void* const* d_in, const int* in_sizes, int n_in,
                              void* d_out, int out_size, void* d_ws, size_t ws_size,
                              hipStream_t stream) {
    const float* X    = (const float*)d_in[0];
    const float* cpt  = (const float*)d_in[1];
    const float* bank = (const float*)d_in[2];
    const float* Wh   = (const float*)d_in[3];
    const float* bh   = (const float*)d_in[4];
    float* out = (float*)d_out;

    float* orig  = out;
    float* ypred = out + Y_OFF;
    float* out3  = out + S_OFF;

    char* w = (char*)d_ws;
    short* Xbf    = (short*)(w);               // 16,777,216 B
    short* WcatT  = (short*)(w + 16777216);    //  4,194,304 B
    short* cptT   = (short*)(w + 20971520);    //    131,072 B
    short* cptR   = (short*)(w + 21102592);    //    131,072 B
    float* key    = (float*)(w + 21233664);    // 25,600,000 B
    float* bank_sq= (float*)(w + 46833664);    //    400,384 B
    float* G      = (float*)(w + 47234048);    //     16,384 B
    float* invG   = (float*)(w + 47250432);    //     16,384 B
    float* M      = (float*)(w + 47266816);    //    262,144 B
    float* cand_v = (float*)(w + 47528960);    //    409,600 B (64*32*50 f32)
    int*   cand_j = (int*)  (w + 47938560);    //    409,600 B
    float* dots   = (float*)(w + 48348160);    //        256 B

    prep_kernel<<<272, 256, 0, stream>>>(cpt, Wh, WcatT, cptT, cptR);
    mid_kernel<<<4887, 256, 0, stream>>>(bank, X, cptT, WcatT, Xbf, key, bank_sq, M, G, invG);
    topA_kernel<<<NCON * NCHUNK, 256, 0, stream>>>(key, cand_v, cand_j);
    m2w2_topB_kernel<<<72, 256, 0, stream>>>(invG, M, cptR, WcatT, cand_v, cand_j, bank_sq, dots);
    pred_fin_kernel<<<1025, 256, 0, stream>>>(Xbf, WcatT, bh, G, dots, orig, ypred, out3);
}